// Round 11
// baseline (90.811 us; speedup 1.0000x reference)
//
#include <hip/hip_runtime.h>

typedef unsigned short u16;
typedef unsigned int u32;
typedef __attribute__((ext_vector_type(4))) float f32x4;
typedef __attribute__((ext_vector_type(8))) short s16x8;

// ---- helpers --------------------------------------------------------------
__device__ __forceinline__ u16 bf16_rne(float f) {
    u32 u = __float_as_uint(f);
    u32 r = u + 0x7FFFu + ((u >> 16) & 1u);
    return (u16)(r >> 16);
}

__device__ __forceinline__ u32 cvt_pk_bf16(float lo, float hi) {
    u32 r;
    asm("v_cvt_pk_bf16_f32 %0, %1, %2" : "=v"(r) : "v"(lo), "v"(hi));
    return r;
}

__device__ __forceinline__ void gl_lds16(const void* g, void* l) {
    __builtin_amdgcn_global_load_lds(
        (const __attribute__((address_space(1))) u32*)g,
        (__attribute__((address_space(3))) u32*)l, 16, 0, 0);
}

#define MFMA16(a, b, c) __builtin_amdgcn_mfma_f32_16x16x32_bf16((a), (b), (c), 0, 0, 0)

// ---- K0: prep — x convert (blocks 0..4095) + both weight transposes --------
__global__ __launch_bounds__(256) void k_prep(const float* __restrict__ x,
                                              const float* __restrict__ w_qkv,
                                              const float* __restrict__ w_out,
                                              u16* __restrict__ xbf,
                                              u16* __restrict__ wqkvt,
                                              u16* __restrict__ woutt) {
    const int tid = threadIdx.x;
    if (blockIdx.x < 4096) {
        int i = blockIdx.x * 256 + tid;
        f32x4 v = *(const f32x4*)(x + (size_t)i * 4);
        u32* p = (u32*)(xbf + (size_t)i * 4);
        p[0] = cvt_pk_bf16(v.x, v.y);
        p[1] = cvt_pk_bf16(v.z, v.w);
        return;
    }
    __shared__ float tile[32][33];
    int idx = blockIdx.x - 4096;           // 0..1023
    int bx_lin = idx & 63, by4 = idx >> 6; // 64 x 16
    const float* in;
    u16* out;
    int C, bxc;
    if (bx_lin < 48) { in = w_qkv; out = wqkvt; C = 1536; bxc = bx_lin; }
    else             { in = w_out; out = woutt; C = 512;  bxc = bx_lin - 48; }
    const int R = 512;
    int bx = bxc * 32;
    int by = by4 * 32;
    int tx = tid & 31;
    int ty = tid >> 5;
#pragma unroll
    for (int i = 0; i < 32; i += 8)
        tile[ty + i][tx] = in[(size_t)(by + ty + i) * C + bx + tx];
    __syncthreads();
#pragma unroll
    for (int i = 0; i < 32; i += 8)
        out[(size_t)(bx + ty + i) * R + by + tx] = bf16_rne(tile[tx][ty + i]);
}

// ---- K1: QKV GEMM  C[8192,1536] = xbf @ w_qkv ------------------------------
// bf16 A via global_load_lds. 1-D grid with XCD-aware remap. Q is prescaled
// by log2(e) at the epilogue so attention can use exp2 directly.
// K written blocked: kRT[bh][jb][i4][jd][il] (i = i4*8+il = n>>4, jb = n&15).
__global__ __launch_bounds__(256) void k_qkv_gemm(
    const u16* __restrict__ xbf, const u16* __restrict__ wt,
    u16* __restrict__ qh, u16* __restrict__ kRT, u16* __restrict__ vT) {
    __shared__ __align__(16) u16 lA[2][128 * 64];
    __shared__ __align__(16) u16 lB[2][128 * 64];
    const int tid = threadIdx.x;
    const int lane = tid & 63, l15 = lane & 15, l4 = lane >> 4;
    const int wid = tid >> 6, wm = wid >> 1, wn = wid & 1;
    const int hw = blockIdx.x;
    const int e = hw & 7, idx = hw >> 3;
    const int m0 = (e + 8 * (idx / 12)) * 128;
    const int c0 = (idx % 12) * 128;

    const char* gA = (const char*)xbf + (size_t)m0 * 1024;
    const char* gB = (const char*)wt + (size_t)c0 * 1024;
    const int srow = tid >> 3;
    const int scol = (tid & 7) * 16;

    const f32x4 z4 = {0.f, 0.f, 0.f, 0.f};
    f32x4 acc[4][4];
#pragma unroll
    for (int i = 0; i < 4; ++i)
#pragma unroll
        for (int j = 0; j < 4; ++j) acc[i][j] = z4;

    auto stage = [&](int buf, int kt) {
#pragma unroll
        for (int q = 0; q < 4; ++q) {
            int row = q * 32 + srow;
            int sc = scol ^ ((row & 7) << 4);
            gl_lds16(gA + (size_t)row * 1024 + kt * 128 + sc,
                     (char*)lA[buf] + q * 4096 + tid * 16);
            gl_lds16(gB + (size_t)row * 1024 + kt * 128 + sc,
                     (char*)lB[buf] + q * 4096 + tid * 16);
        }
    };

    stage(0, 0);
    __syncthreads();
    for (int kt = 0; kt < 8; ++kt) {
        int buf = kt & 1;
        if (kt < 7) stage(buf ^ 1, kt + 1);
        s16x8 af[4][2], bfr[4][2];
#pragma unroll
        for (int i = 0; i < 4; ++i)
#pragma unroll
            for (int k2 = 0; k2 < 2; ++k2) {
                int ra = wm * 64 + i * 16 + l15;
                int ca = (k2 * 64 + l4 * 16) ^ ((ra & 7) << 4);
                af[i][k2] = *(const s16x8*)((const char*)lA[buf] + ra * 128 + ca);
                int rb = wn * 64 + i * 16 + l15;
                int cb = (k2 * 64 + l4 * 16) ^ ((rb & 7) << 4);
                bfr[i][k2] = *(const s16x8*)((const char*)lB[buf] + rb * 128 + cb);
            }
        __builtin_amdgcn_s_setprio(1);
#pragma unroll
        for (int i = 0; i < 4; ++i)
#pragma unroll
            for (int j = 0; j < 4; ++j)
#pragma unroll
                for (int k2 = 0; k2 < 2; ++k2)
                    acc[i][j] = MFMA16(af[i][k2], bfr[j][k2], acc[i][j]);
        __builtin_amdgcn_s_setprio(0);
        __syncthreads();
    }

    // ---- epilogue: C tile -> LDS (32KB, reuse lA) -> coalesced stores ------
    char* ct = (char*)lA;
    const int which = c0 >> 9;            // 0=q 1=k 2=v
    const int hb = (c0 & 511) >> 6;       // head base within segment
    const int b = m0 >> 10;               // batch
    const int n0 = m0 & 1023;             // token base within batch
    const int i4 = (m0 >> 7) & 7;         // i-block within batch (for kRT)
    const float qsc = (which == 0) ? 1.4426950408889634f : 1.0f;

    if (which != 2) {  // row-major [row][128 cols], swizzled
#pragma unroll
        for (int i = 0; i < 4; ++i)
#pragma unroll
            for (int j = 0; j < 4; ++j) {
                int col = wn * 64 + j * 16 + l15;
#pragma unroll
                for (int r = 0; r < 4; ++r) {
                    int rr = wm * 64 + i * 16 + l4 * 4 + r;
                    *(u16*)(ct + rr * 256 + ((col * 2) ^ ((rr & 7) << 4))) =
                        bf16_rne(acc[i][j][r] * qsc);
                }
            }
    } else {  // transposed [col][128 rows], swizzled (vT needs n-contiguous)
#pragma unroll
        for (int i = 0; i < 4; ++i)
#pragma unroll
            for (int j = 0; j < 4; ++j) {
                int col = wn * 64 + j * 16 + l15;
#pragma unroll
                for (int r = 0; r < 4; ++r) {
                    int rr = wm * 64 + i * 16 + l4 * 4 + r;
                    *(u16*)(ct + col * 256 + ((rr * 2) ^ ((col & 7) << 4))) =
                        bf16_rne(acc[i][j][r]);
                }
            }
    }
    __syncthreads();

    if (which == 0) {
#pragma unroll
        for (int p = 0; p < 8; ++p) {
            int cid = p * 256 + tid;
            int row = cid >> 4, sub = cid & 15;
            s16x8 v = *(const s16x8*)(ct + row * 256 + ((sub * 16) ^ ((row & 7) << 4)));
            int bh = b * 8 + hb + (sub >> 3);
            *(s16x8*)((char*)qh + ((size_t)bh * 1024 + n0 + row) * 128 +
                      (sub & 7) * 16) = v;
        }
    } else if (which == 1) {
#pragma unroll
        for (int p = 0; p < 8; ++p) {
            int cid = p * 256 + tid;
            int h = cid >> 10, jb = (cid >> 6) & 15, jd = cid & 63;
            int colb = ((h * 64 + jd) * 2) ^ ((jb & 7) << 4);
            s16x8 v;
#pragma unroll
            for (int ii = 0; ii < 8; ++ii)
                v[ii] = *(const short*)(ct + (jb + ii * 16) * 256 + colb);
            int bh = b * 8 + hb + h;
            *(s16x8*)((char*)kRT + (size_t)bh * 131072 + jb * 8192 + i4 * 1024 +
                      jd * 16) = v;
        }
    } else {
#pragma unroll
        for (int p = 0; p < 8; ++p) {
            int cid = p * 256 + tid;
            int cl = cid >> 4, nc = cid & 15;
            s16x8 v = *(const s16x8*)(ct + cl * 256 + ((nc * 16) ^ ((cl & 7) << 4)));
            int bh = b * 8 + hb + (cl >> 6);
            *(s16x8*)((char*)vT + ((size_t)bh * 64 + (cl & 63)) * 2048 + n0 * 2 +
                      nc * 16) = v;
        }
    }
}

// ---- K3: fused attention — K direct global->VGPR, V via LDS DMA ------------
// 256 thr / 4 waves x 16 q-rows, 64-row tile, grid (64 bh, 16 mt).
// kRT blocked layout makes per-lane K-frag addresses 256B-coalesced; the 4
// waves share the 8KB tile via L1. K regs double-buffered (bkA/bkB, manual
// 2x unroll). V double-buffered in LDS. LDS = 24KB (Q/P 8K + V 2x8K).
__global__ __launch_bounds__(256) void k_attn(
    const u16* __restrict__ qh, const u16* __restrict__ kRT,
    const u16* __restrict__ vT, u16* __restrict__ attn_out) {
    __shared__ __align__(16) char smem[24576];
    char* qtile = smem;               // 8KB Q staging; then per-wave P; then O
    char* vtb = smem + 8192;          // 2 x 8KB V tiles [d][n] swizzled

    const int tid = threadIdx.x;
    const int lane = tid & 63, l15 = lane & 15, l4 = lane >> 4;
    const int wid = tid >> 6;         // 0..3
    const int bh = blockIdx.x, mt = blockIdx.y;

    const char* kb = (const char*)kRT + (size_t)bh * 131072;
    const char* vb = (const char*)vT + (size_t)bh * 131072;
    const int srow = tid >> 3;        // 0..31
    const int scol = (tid & 7) * 16;

    // per-lane K-frag base: frag(n4,k2) at kfb + jb*8192 + k2*4096 + n4*256
    const char* kfb = kb + l4 * 1024 + l15 * 16;

    // stage Q (64 rows, swizzled) + V tile 0; K tile 0 -> regs
    {
        const char* gq = (const char*)qh + ((size_t)bh * 1024 + mt * 64) * 128;
#pragma unroll
        for (int q = 0; q < 2; ++q) {
            int row = q * 32 + srow;
            int sc = scol ^ ((row & 7) << 4);
            gl_lds16(gq + (size_t)row * 128 + sc, qtile + q * 4096 + tid * 16);
        }
#pragma unroll
        for (int q = 0; q < 2; ++q) {
            int jd = q * 32 + srow;
            int sc = scol ^ ((jd & 7) << 4);
            gl_lds16(vb + (size_t)jd * 2048 + sc, vtb + q * 4096 + tid * 16);
        }
    }
    s16x8 bkA[4][2], bkB[4][2];
#pragma unroll
    for (int n4 = 0; n4 < 4; ++n4)
#pragma unroll
        for (int k2 = 0; k2 < 2; ++k2)
            bkA[n4][k2] = *(const s16x8*)(kfb + k2 * 4096 + n4 * 256);
    __syncthreads();

    s16x8 qf[2];  // B-frag: lane holds Q[m = wid*16 + l15][k-chunk]
#pragma unroll
    for (int k2 = 0; k2 < 2; ++k2) {
        int row = wid * 16 + l15;
        int cq = (k2 * 64 + l4 * 16) ^ ((row & 7) << 4);
        qf[k2] = *(const s16x8*)(qtile + row * 128 + cq);
    }
    __syncthreads();  // qtile now free -> per-wave P region (2KB each)

    char* ptw = smem + wid * 2048;  // per-wave P: [16 rows m][64 n], swizzled

    const f32x4 z4 = {0.f, 0.f, 0.f, 0.f};
    f32x4 o[4];     // O^T frag: o[d4][r] at d = d4*16 + l4*4 + r, m = l15
    float den = 0.f;
#pragma unroll
    for (int d4 = 0; d4 < 4; ++d4) o[d4] = z4;

    auto body = [&](int jb, s16x8 (&bku)[4][2], s16x8 (&bkp)[4][2]) {
        const int buf = jb & 1;
        if (jb < 15) {  // prefetch K jb+1 -> regs, V jb+1 -> LDS (other buf)
            const char* kn = kfb + (size_t)(jb + 1) * 8192;
#pragma unroll
            for (int n4 = 0; n4 < 4; ++n4)
#pragma unroll
                for (int k2 = 0; k2 < 2; ++k2)
                    bkp[n4][k2] = *(const s16x8*)(kn + k2 * 4096 + n4 * 256);
            int nb = jb + 1, bufn = buf ^ 1;
#pragma unroll
            for (int q = 0; q < 2; ++q) {
                int jd = q * 32 + srow;
                int sc = scol ^ ((jd & 7) << 4);
                gl_lds16(vb + (size_t)jd * 2048 + nb * 128 + sc,
                         vtb + bufn * 8192 + q * 4096 + tid * 16);
            }
        }
        const char* vt = vtb + buf * 8192;

        // S^T = Ktile @ Q^T (A-frags in regs)
        f32x4 s[4];
        __builtin_amdgcn_s_setprio(1);
#pragma unroll
        for (int n4 = 0; n4 < 4; ++n4) {
            s[n4] = z4;
#pragma unroll
            for (int k2 = 0; k2 < 2; ++k2)
                s[n4] = MFMA16(bku[n4][k2], qf[k2], s[n4]);
        }
        __builtin_amdgcn_s_setprio(0);

        // P = exp2(S) (Q pre-scaled): lane-local row m = l15; packed b64 write
#pragma unroll
        for (int n4 = 0; n4 < 4; ++n4) {
            float e0 = exp2f(s[n4][0]);
            float e1 = exp2f(s[n4][1]);
            float e2 = exp2f(s[n4][2]);
            float e3 = exp2f(s[n4][3]);
            den += (e0 + e1) + (e2 + e3);
            uint2 w;
            w.x = cvt_pk_bf16(e0, e1);
            w.y = cvt_pk_bf16(e2, e3);
            *(uint2*)(ptw + l15 * 128 +
                      ((n4 * 32 + l4 * 8) ^ ((l15 & 7) << 4))) = w;
        }

        // V fragments (A-frag: rows d) from LDS
        s16x8 bv[4][2];
#pragma unroll
        for (int d4 = 0; d4 < 4; ++d4)
#pragma unroll
            for (int k2 = 0; k2 < 2; ++k2) {
                int rn = d4 * 16 + l15;
                int cb = (k2 * 64 + l4 * 16) ^ ((rn & 7) << 4);
                bv[d4][k2] = *(const s16x8*)(vt + rn * 128 + cb);
            }

        // P B-frags back (wave-private): row l15, 16B chunk
        s16x8 pa[2];
#pragma unroll
        for (int k2 = 0; k2 < 2; ++k2)
            pa[k2] = *(const s16x8*)(ptw + l15 * 128 +
                                     ((k2 * 64 + l4 * 16) ^ ((l15 & 7) << 4)));

        // O^T += Vtile @ P^T
        __builtin_amdgcn_s_setprio(1);
#pragma unroll
        for (int d4 = 0; d4 < 4; ++d4)
#pragma unroll
            for (int k2 = 0; k2 < 2; ++k2)
                o[d4] = MFMA16(bv[d4][k2], pa[k2], o[d4]);
        __builtin_amdgcn_s_setprio(0);

        if (jb < 15) __syncthreads();
    };

#pragma unroll 1
    for (int jj = 0; jj < 8; ++jj) {
        body(2 * jj, bkA, bkB);
        body(2 * jj + 1, bkB, bkA);
    }

    // den: sum over the 4 lanes sharing l15 (l4 = 0..3)
    den += __shfl_xor(den, 16);
    den += __shfl_xor(den, 32);
    float inv = 1.0f / den;

    // ---- epilogue: O -> LDS [64 rows m][64 d] (b64 packed), then coalesced
    {
        int row = wid * 16 + l15;
        char* ow = smem + row * 128;
#pragma unroll
        for (int d4 = 0; d4 < 4; ++d4) {
            uint2 w;
            w.x = cvt_pk_bf16(o[d4][0] * inv, o[d4][1] * inv);
            w.y = cvt_pk_bf16(o[d4][2] * inv, o[d4][3] * inv);
            *(uint2*)(ow + ((d4 * 32 + l4 * 8) ^ ((row & 7) << 4))) = w;
        }
    }
    __syncthreads();

    // coalesced store: attn_out[b*1024+n][h*64+d] -- 128B head-chunk per row
    {
        char* dst = (char*)attn_out + ((size_t)(bh >> 3) * 1024 + mt * 64) * 1024 +
                    (bh & 7) * 128;
#pragma unroll
        for (int p = 0; p < 2; ++p) {
            int cid = p * 256 + tid;
            int row = cid >> 3, sub = cid & 7;
            s16x8 v = *(const s16x8*)(smem + row * 128 +
                                      ((sub * 16) ^ ((row & 7) << 4)));
            *(s16x8*)(dst + (size_t)row * 1024 + sub * 16) = v;
        }
    }
}

// ---- K4: out projection + LayerNorm + residual, fused -----------------------
__global__ __launch_bounds__(512) void k_out_ln(
    const u16* __restrict__ aout, const u16* __restrict__ wt,
    const float* __restrict__ bias, const float* __restrict__ x,
    const float* __restrict__ g, const float* __restrict__ bb,
    float* __restrict__ out) {
    __shared__ __align__(16) char smem[131072];  // B dbuf 2x64KB; then proj f32
    char* lB[2] = {smem, smem + 65536};
    const int tid = threadIdx.x;
    const int lane = tid & 63, l15 = lane & 15, l4 = lane >> 4;
    const int wid = tid >> 6, wm = wid >> 2, wn = wid & 3;
    const int m0 = blockIdx.x * 32;

    // A in registers: rows m0 + wm*16 + l15, k-chunk kk*32 + l4*8
    s16x8 af[16];
    {
        const char* arow = (const char*)aout + (size_t)(m0 + wm * 16 + l15) * 1024;
#pragma unroll
        for (int kk = 0; kk < 16; ++kk)
            af[kk] = *(const s16x8*)(arow + kk * 64 + l4 * 16);
    }

    auto stageB = [&](int buf, int kt) {
#pragma unroll
        for (int p = 0; p < 8; ++p) {
            int cid = p * 512 + tid;          // 0..4095 chunk id
            int n = cid >> 3, cc = cid & 7;
            int sc = (cc * 16) ^ ((n & 7) << 4);
            gl_lds16((const char*)wt + (size_t)n * 1024 + kt * 128 + sc,
                     lB[buf] + cid * 16);
        }
    };

    const f32x4 z4 = {0.f, 0.f, 0.f, 0.f};
    f32x4 acc[8];
#pragma unroll
    for (int j = 0; j < 8; ++j) acc[j] = z4;

    stageB(0, 0);
    __syncthreads();
    for (int kt = 0; kt < 8; ++kt) {
        int buf = kt & 1;
        if (kt < 7) stageB(buf ^ 1, kt + 1);
        s16x8 bf2[8][2];
#pragma unroll
        for (int j = 0; j < 8; ++j)
#pragma unroll
            for (int q = 0; q < 2; ++q) {
                int n = wn * 128 + j * 16 + l15;
                int cb = (q * 64 + l4 * 16) ^ ((n & 7) << 4);
                bf2[j][q] = *(const s16x8*)(lB[buf] + n * 128 + cb);
            }
        __builtin_amdgcn_s_setprio(1);
#pragma unroll
        for (int j = 0; j < 8; ++j)
#pragma unroll
            for (int q = 0; q < 2; ++q)
                acc[j] = MFMA16(af[kt * 2 + q], bf2[j][q], acc[j]);
        __builtin_amdgcn_s_setprio(0);
        __syncthreads();
    }

    // proj + bias -> LDS f32 [32][512], 16B-swizzled
#pragma unroll
    for (int j = 0; j < 8; ++j) {
        int col = wn * 128 + j * 16 + l15;
        float bo = bias[col];
#pragma unroll
        for (int r = 0; r < 4; ++r) {
            int row = wm * 16 + l4 * 4 + r;
            *(float*)(smem + row * 2048 + ((col * 4) ^ ((row & 7) << 4))) =
                acc[j][r] + bo;
        }
    }
    __syncthreads();

    // LN + residual: wave wid handles rows wid*4 .. +4; lane owns cols lane*8..+8
    f32x4 g0 = *(const f32x4*)(g + lane * 8);
    f32x4 g1 = *(const f32x4*)(g + lane * 8 + 4);
    f32x4 b0 = *(const f32x4*)(bb + lane * 8);
    f32x4 b1 = *(const f32x4*)(bb + lane * 8 + 4);
#pragma unroll
    for (int rr = 0; rr < 4; ++rr) {
        int row = wid * 4 + rr;
        int sw = (row & 7) << 4;
        f32x4 v0 = *(const f32x4*)(smem + row * 2048 + ((lane * 32) ^ sw));
        f32x4 v1 = *(const f32x4*)(smem + row * 2048 + ((lane * 32 + 16) ^ sw));
        float s = v0.x + v0.y + v0.z + v0.w + v1.x + v1.y + v1.z + v1.w;
        float sq = v0.x * v0.x + v0.y * v0.y + v0.z * v0.z + v0.w * v0.w +
                   v1.x * v1.x + v1.y * v1.y + v1.z * v1.z + v1.w * v1.w;
#pragma unroll
        for (int m = 1; m < 64; m <<= 1) {
            s += __shfl_xor(s, m);
            sq += __shfl_xor(sq, m);
        }
        float mu = s * (1.0f / 512.0f);
        float var = sq * (1.0f / 512.0f) - mu * mu;
        float rstd = rsqrtf(var + 1e-5f);

        const float* xr = x + (size_t)(m0 + row) * 512 + lane * 8;
        f32x4 x0 = *(const f32x4*)(xr);
        f32x4 x1 = *(const f32x4*)(xr + 4);
        f32x4 r0, r1;
#pragma unroll
        for (int u = 0; u < 4; ++u) {
            r0[u] = (v0[u] - mu) * rstd * g0[u] + b0[u] + x0[u];
            r1[u] = (v1[u] - mu) * rstd * g1[u] + b1[u] + x1[u];
        }
        float* orow = out + (size_t)(m0 + row) * 512 + lane * 8;
        *(f32x4*)(orow) = r0;
        *(f32x4*)(orow + 4) = r1;
    }
}

// ---- launch -----------------------------------------------------------------
extern "C" void kernel_launch(void* const* d_in, const int* in_sizes, int n_in,
                              void* d_out, int out_size, void* d_ws, size_t ws_size,
                              hipStream_t stream) {
    const float* x = (const float*)d_in[0];
    const float* w_qkv = (const float*)d_in[1];
    const float* w_out = (const float*)d_in[2];
    const float* b_out = (const float*)d_in[3];
    const float* ln_g = (const float*)d_in[4];
    const float* ln_b = (const float*)d_in[5];
    float* out = (float*)d_out;
    char* ws = (char*)d_ws;

    u16* xbf = (u16*)(ws + 0);             // 8 MiB   [8192][512] bf16
    u16* wqkvt = (u16*)(ws + 8388608);     // 1.5 MiB [1536][512] bf16
    u16* woutt = (u16*)(ws + 9961472);     // 0.5 MiB [512][512]  bf16
    u16* qh = (u16*)(ws + 10485760);       // 8 MiB   [64][1024][64]
    u16* kRT = (u16*)(ws + 18874368);      // 8 MiB   [64][16][8][64][8]
    u16* vT = (u16*)(ws + 27262976);       // 8 MiB   [64][64][1024]
    u16* aout = (u16*)(ws + 35651584);     // 8 MiB   [8192][512]

    k_prep<<<5120, 256, 0, stream>>>(x, w_qkv, w_out, xbf, wqkvt, woutt);
    k_qkv_gemm<<<768, 256, 0, stream>>>(xbf, wqkvt, qh, kRT, vT);
    k_attn<<<dim3(64, 16), 256, 0, stream>>>(qh, kRT, vT, aout);
    k_out_ln<<<256, 512, 0, stream>>>(aout, woutt, b_out, x, ln_g, ln_b, out);
}

// Round 13
// 80.390 us; speedup vs baseline: 1.1296x; 1.1296x over previous
//
#include <hip/hip_runtime.h>

typedef unsigned short u16;
typedef unsigned int u32;
typedef __attribute__((ext_vector_type(4))) float f32x4;
typedef __attribute__((ext_vector_type(16))) float f32x16;
typedef __attribute__((ext_vector_type(8))) short s16x8;

// ---- helpers --------------------------------------------------------------
__device__ __forceinline__ u16 bf16_rne(float f) {
    u32 u = __float_as_uint(f);
    u32 r = u + 0x7FFFu + ((u >> 16) & 1u);
    return (u16)(r >> 16);
}

__device__ __forceinline__ u32 cvt_pk_bf16(float lo, float hi) {
    u32 r;
    asm("v_cvt_pk_bf16_f32 %0, %1, %2" : "=v"(r) : "v"(lo), "v"(hi));
    return r;
}

__device__ __forceinline__ void gl_lds16(const void* g, void* l) {
    __builtin_amdgcn_global_load_lds(
        (const __attribute__((address_space(1))) u32*)g,
        (__attribute__((address_space(3))) u32*)l, 16, 0, 0);
}

#define MFMA16(a, b, c) __builtin_amdgcn_mfma_f32_16x16x32_bf16((a), (b), (c), 0, 0, 0)
#define MFMA32(a, b, c) __builtin_amdgcn_mfma_f32_32x32x16_bf16((a), (b), (c), 0, 0, 0)

union frag_u { u32 u[4]; s16x8 v; };

// ---- K0: prep — x convert (blocks 0..4095) + both weight transposes --------
__global__ __launch_bounds__(256) void k_prep(const float* __restrict__ x,
                                              const float* __restrict__ w_qkv,
                                              const float* __restrict__ w_out,
                                              u16* __restrict__ xbf,
                                              u16* __restrict__ wqkvt,
                                              u16* __restrict__ woutt) {
    const int tid = threadIdx.x;
    if (blockIdx.x < 4096) {
        int i = blockIdx.x * 256 + tid;
        f32x4 v = *(const f32x4*)(x + (size_t)i * 4);
        u32* p = (u32*)(xbf + (size_t)i * 4);
        p[0] = cvt_pk_bf16(v.x, v.y);
        p[1] = cvt_pk_bf16(v.z, v.w);
        return;
    }
    __shared__ float tile[32][33];
    int idx = blockIdx.x - 4096;           // 0..1023
    int bx_lin = idx & 63, by4 = idx >> 6; // 64 x 16
    const float* in;
    u16* out;
    int C, bxc;
    if (bx_lin < 48) { in = w_qkv; out = wqkvt; C = 1536; bxc = bx_lin; }
    else             { in = w_out; out = woutt; C = 512;  bxc = bx_lin - 48; }
    const int R = 512;
    int bx = bxc * 32;
    int by = by4 * 32;
    int tx = tid & 31;
    int ty = tid >> 5;
#pragma unroll
    for (int i = 0; i < 32; i += 8)
        tile[ty + i][tx] = in[(size_t)(by + ty + i) * C + bx + tx];
    __syncthreads();
#pragma unroll
    for (int i = 0; i < 32; i += 8)
        out[(size_t)(bx + ty + i) * R + by + tx] = bf16_rne(tile[tx][ty + i]);
}

// ---- K1: QKV GEMM  C[8192,1536] = xbf @ w_qkv ------------------------------
// bf16 A via global_load_lds. 1-D grid with XCD-aware remap. Q is prescaled
// by log2(e) at the epilogue so attention can use exp2 directly.
// K written blocked: kRT[bh][jb][i4][jd][il] (i = i4*8+il = n>>4, jb = n&15).
__global__ __launch_bounds__(256) void k_qkv_gemm(
    const u16* __restrict__ xbf, const u16* __restrict__ wt,
    u16* __restrict__ qh, u16* __restrict__ kRT, u16* __restrict__ vT) {
    __shared__ __align__(16) u16 lA[2][128 * 64];
    __shared__ __align__(16) u16 lB[2][128 * 64];
    const int tid = threadIdx.x;
    const int lane = tid & 63, l15 = lane & 15, l4 = lane >> 4;
    const int wid = tid >> 6, wm = wid >> 1, wn = wid & 1;
    const int hw = blockIdx.x;
    const int e = hw & 7, idx = hw >> 3;
    const int m0 = (e + 8 * (idx / 12)) * 128;
    const int c0 = (idx % 12) * 128;

    const char* gA = (const char*)xbf + (size_t)m0 * 1024;
    const char* gB = (const char*)wt + (size_t)c0 * 1024;
    const int srow = tid >> 3;
    const int scol = (tid & 7) * 16;

    const f32x4 z4 = {0.f, 0.f, 0.f, 0.f};
    f32x4 acc[4][4];
#pragma unroll
    for (int i = 0; i < 4; ++i)
#pragma unroll
        for (int j = 0; j < 4; ++j) acc[i][j] = z4;

    auto stage = [&](int buf, int kt) {
#pragma unroll
        for (int q = 0; q < 4; ++q) {
            int row = q * 32 + srow;
            int sc = scol ^ ((row & 7) << 4);
            gl_lds16(gA + (size_t)row * 1024 + kt * 128 + sc,
                     (char*)lA[buf] + q * 4096 + tid * 16);
            gl_lds16(gB + (size_t)row * 1024 + kt * 128 + sc,
                     (char*)lB[buf] + q * 4096 + tid * 16);
        }
    };

    stage(0, 0);
    __syncthreads();
    for (int kt = 0; kt < 8; ++kt) {
        int buf = kt & 1;
        if (kt < 7) stage(buf ^ 1, kt + 1);
        s16x8 af[4][2], bfr[4][2];
#pragma unroll
        for (int i = 0; i < 4; ++i)
#pragma unroll
            for (int k2 = 0; k2 < 2; ++k2) {
                int ra = wm * 64 + i * 16 + l15;
                int ca = (k2 * 64 + l4 * 16) ^ ((ra & 7) << 4);
                af[i][k2] = *(const s16x8*)((const char*)lA[buf] + ra * 128 + ca);
                int rb = wn * 64 + i * 16 + l15;
                int cb = (k2 * 64 + l4 * 16) ^ ((rb & 7) << 4);
                bfr[i][k2] = *(const s16x8*)((const char*)lB[buf] + rb * 128 + cb);
            }
        __builtin_amdgcn_s_setprio(1);
#pragma unroll
        for (int i = 0; i < 4; ++i)
#pragma unroll
            for (int j = 0; j < 4; ++j)
#pragma unroll
                for (int k2 = 0; k2 < 2; ++k2)
                    acc[i][j] = MFMA16(af[i][k2], bfr[j][k2], acc[i][j]);
        __builtin_amdgcn_s_setprio(0);
        __syncthreads();
    }

    // ---- epilogue: C tile -> LDS (32KB, reuse lA) -> coalesced stores ------
    char* ct = (char*)lA;
    const int which = c0 >> 9;            // 0=q 1=k 2=v
    const int hb = (c0 & 511) >> 6;       // head base within segment
    const int b = m0 >> 10;               // batch
    const int n0 = m0 & 1023;             // token base within batch
    const int i4 = (m0 >> 7) & 7;         // i-block within batch (for kRT)
    const float qsc = (which == 0) ? 1.4426950408889634f : 1.0f;

    if (which != 2) {  // row-major [row][128 cols], swizzled
#pragma unroll
        for (int i = 0; i < 4; ++i)
#pragma unroll
            for (int j = 0; j < 4; ++j) {
                int col = wn * 64 + j * 16 + l15;
#pragma unroll
                for (int r = 0; r < 4; ++r) {
                    int rr = wm * 64 + i * 16 + l4 * 4 + r;
                    *(u16*)(ct + rr * 256 + ((col * 2) ^ ((rr & 7) << 4))) =
                        bf16_rne(acc[i][j][r] * qsc);
                }
            }
    } else {  // transposed [col][128 rows], swizzled (vT needs n-contiguous)
#pragma unroll
        for (int i = 0; i < 4; ++i)
#pragma unroll
            for (int j = 0; j < 4; ++j) {
                int col = wn * 64 + j * 16 + l15;
#pragma unroll
                for (int r = 0; r < 4; ++r) {
                    int rr = wm * 64 + i * 16 + l4 * 4 + r;
                    *(u16*)(ct + col * 256 + ((rr * 2) ^ ((col & 7) << 4))) =
                        bf16_rne(acc[i][j][r]);
                }
            }
    }
    __syncthreads();

    if (which == 0) {
#pragma unroll
        for (int p = 0; p < 8; ++p) {
            int cid = p * 256 + tid;
            int row = cid >> 4, sub = cid & 15;
            s16x8 v = *(const s16x8*)(ct + row * 256 + ((sub * 16) ^ ((row & 7) << 4)));
            int bh = b * 8 + hb + (sub >> 3);
            *(s16x8*)((char*)qh + ((size_t)bh * 1024 + n0 + row) * 128 +
                      (sub & 7) * 16) = v;
        }
    } else if (which == 1) {
#pragma unroll
        for (int p = 0; p < 8; ++p) {
            int cid = p * 256 + tid;
            int h = cid >> 10, jb = (cid >> 6) & 15, jd = cid & 63;
            int colb = ((h * 64 + jd) * 2) ^ ((jb & 7) << 4);
            s16x8 v;
#pragma unroll
            for (int ii = 0; ii < 8; ++ii)
                v[ii] = *(const short*)(ct + (jb + ii * 16) * 256 + colb);
            int bh = b * 8 + hb + h;
            *(s16x8*)((char*)kRT + (size_t)bh * 131072 + jb * 8192 + i4 * 1024 +
                      jd * 16) = v;
        }
    } else {
#pragma unroll
        for (int p = 0; p < 8; ++p) {
            int cid = p * 256 + tid;
            int cl = cid >> 4, nc = cid & 15;
            s16x8 v = *(const s16x8*)(ct + cl * 256 + ((nc * 16) ^ ((cl & 7) << 4)));
            int bh = b * 8 + hb + (cl >> 6);
            *(s16x8*)((char*)vT + ((size_t)bh * 64 + (cl & 63)) * 2048 + n0 * 2 +
                      nc * 16) = v;
        }
    }
}

// ---- K3: fused attention, 32x32 MFMA + in-register P ------------------------
// 256 thr / 4 waves x 32 q-rows = 128-row tile, grid (64 bh, 8 mt).
// S^T = mfma32(K-frag, Q-frag): C col = m = lane&31, 32 n-rows per lane.
// P in registers; sg-half exchange via shfl_xor(32) (verified) + selects:
// word-pair (lo,hi): c = shfl_xor(sg?lo:hi,32); wl = sg?c:lo; wh = sg?hi:c.
// den = per-lane sum + shfl_xor(32). K tile LINEAR (blocked kRT); V swizzled.
__global__ __launch_bounds__(256, 2) void k_attn(
    const u16* __restrict__ qh, const u16* __restrict__ kRT,
    const u16* __restrict__ vT, u16* __restrict__ attn_out) {
    __shared__ __align__(16) char smem[49152];
    char* qtile = smem;               // 16KB Q staging; later O staging
    char* ktb = smem + 16384;         // 2 x 8KB K tiles, linear [i4][jd][il]
    char* vtb = smem + 32768;         // 2 x 8KB V tiles [d][n], swizzled

    const int tid = threadIdx.x;
    const int lane = tid & 63, l31 = lane & 31, sg = lane >> 5;
    const int wv = tid >> 6;          // 0..3
    const int bh = blockIdx.x, mt = blockIdx.y;

    const char* kb = (const char*)kRT + (size_t)bh * 131072;
    const char* vb = (const char*)vT + (size_t)bh * 131072;
    const int srow = tid >> 3;        // 0..31
    const int scol = (tid & 7) * 16;

    // stage Q (128 rows, swizzled) + K tile 0 (linear) + V tile 0 (swizzled)
    {
        const char* gq = (const char*)qh + ((size_t)bh * 1024 + mt * 128) * 128;
#pragma unroll
        for (int q = 0; q < 4; ++q) {
            int row = q * 32 + srow;
            int sc = scol ^ ((row & 7) << 4);
            gl_lds16(gq + (size_t)row * 128 + sc, qtile + q * 4096 + tid * 16);
        }
#pragma unroll
        for (int q = 0; q < 2; ++q) {
            gl_lds16(kb + (q * 256 + tid) * 16, ktb + (q * 256 + tid) * 16);
            int row = q * 32 + srow;
            gl_lds16(vb + (size_t)row * 2048 + (scol ^ ((row & 7) << 4)),
                     vtb + q * 4096 + tid * 16);
        }
    }
    __syncthreads();

    // Q B-frags: col m = wv*32 + l31, k-chunk iq*16 + sg*8 (bytes iq*32+sg*16)
    const int qrow = wv * 32 + l31;
    s16x8 qf[4];
#pragma unroll
    for (int iq = 0; iq < 4; ++iq)
        qf[iq] = *(const s16x8*)(qtile + qrow * 128 +
                                 ((iq * 32 + sg * 16) ^ ((qrow & 7) << 4)));

    f32x16 zz;
#pragma unroll
    for (int r = 0; r < 16; ++r) zz[r] = 0.f;
    f32x16 o0 = zz, o1 = zz;
    float den = 0.f;

    for (int jb = 0; jb < 16; ++jb) {
        const int buf = jb & 1;
        if (jb < 15) {  // prefetch next K/V
            int nb = jb + 1, bufn = buf ^ 1;
#pragma unroll
            for (int q = 0; q < 2; ++q) {
                gl_lds16(kb + (size_t)nb * 8192 + (q * 256 + tid) * 16,
                         ktb + bufn * 8192 + (q * 256 + tid) * 16);
                int row = q * 32 + srow;
                gl_lds16(vb + (size_t)row * 2048 + nb * 128 +
                             (scol ^ ((row & 7) << 4)),
                         vtb + bufn * 8192 + q * 4096 + tid * 16);
            }
        }
        const char* kt = ktb + buf * 8192;
        const char* vt = vtb + buf * 8192;

        // S^T: A-frag = K'^T rows n (l31 / l31+32), k = i-chunk
        f32x16 s0 = zz, s1 = zz;
        __builtin_amdgcn_s_setprio(1);
#pragma unroll
        for (int iq = 0; iq < 4; ++iq) {
            const char* ka = kt + (2 * iq + sg) * 1024 + l31 * 16;
            s16x8 a0 = *(const s16x8*)(ka);
            s16x8 a1 = *(const s16x8*)(ka + 512);
            s0 = MFMA32(a0, qf[iq], s0);
            s1 = MFMA32(a1, qf[iq], s1);
        }
        __builtin_amdgcn_s_setprio(0);

        // P = exp2(S) in-register; pack to bf16 pairs
        u32 u0[8], u1[8];
        {
            f32x16 e0, e1;
#pragma unroll
            for (int r = 0; r < 16; ++r) {
                e0[r] = exp2f(s0[r]);
                e1[r] = exp2f(s1[r]);
                den += e0[r] + e1[r];
            }
#pragma unroll
            for (int j = 0; j < 8; ++j) {
                u0[j] = cvt_pk_bf16(e0[2 * j], e0[2 * j + 1]);
                u1[j] = cvt_pk_bf16(e1[2 * j], e1[2 * j + 1]);
            }
        }
        // sg-half exchange: lane's C-layout n-set {t+8g+4sg} -> B-frag n-set
        // {sg*8+j}. Per word-pair (lo,hi): c = shfl_xor(sg?lo:hi, 32);
        // wl = sg?c:lo; wh = sg?hi:c.
        s16x8 pa[4];
        {
            auto mix = [&](u32 lo, u32 hi, u32& wl, u32& wh) {
                u32 c = (u32)__shfl_xor((int)(sg ? lo : hi), 32);
                wl = sg ? c : lo;
                wh = sg ? hi : c;
            };
            frag_u f;
            mix(u0[0], u0[2], f.u[0], f.u[2]);
            mix(u0[1], u0[3], f.u[1], f.u[3]);
            pa[0] = f.v;
            mix(u0[4], u0[6], f.u[0], f.u[2]);
            mix(u0[5], u0[7], f.u[1], f.u[3]);
            pa[1] = f.v;
            mix(u1[0], u1[2], f.u[0], f.u[2]);
            mix(u1[1], u1[3], f.u[1], f.u[3]);
            pa[2] = f.v;
            mix(u1[4], u1[6], f.u[0], f.u[2]);
            mix(u1[5], u1[7], f.u[1], f.u[3]);
            pa[3] = f.v;
        }

        // O^T += V^T @ P^T : A-frag = vT rows d, k = n-chunk
        __builtin_amdgcn_s_setprio(1);
#pragma unroll
        for (int nq = 0; nq < 4; ++nq) {
            int cb = (nq * 32 + sg * 16) ^ ((l31 & 7) << 4);
            s16x8 v0 = *(const s16x8*)(vt + l31 * 128 + cb);
            s16x8 v1 = *(const s16x8*)(vt + (32 + l31) * 128 + cb);
            o0 = MFMA32(v0, pa[nq], o0);
            o1 = MFMA32(v1, pa[nq], o1);
        }
        __builtin_amdgcn_s_setprio(0);

        if (jb < 15) __syncthreads();
    }

    // den: lane holds half the n-range; partner lane^32 has the other half
    den += __shfl_xor(den, 32);
    float inv = 1.0f / den;

    // ---- epilogue: O -> LDS [128 rows m][64 d] (b64 packed, swizzled) ------
    {
        char* ow = smem + qrow * 128;
        int sw = (qrow & 7) << 4;
#pragma unroll
        for (int g = 0; g < 4; ++g) {
            uint2 w;
            w.x = cvt_pk_bf16(o0[4 * g] * inv, o0[4 * g + 1] * inv);
            w.y = cvt_pk_bf16(o0[4 * g + 2] * inv, o0[4 * g + 3] * inv);
            *(uint2*)(ow + ((16 * g + 8 * sg) ^ sw)) = w;
            w.x = cvt_pk_bf16(o1[4 * g] * inv, o1[4 * g + 1] * inv);
            w.y = cvt_pk_bf16(o1[4 * g + 2] * inv, o1[4 * g + 3] * inv);
            *(uint2*)(ow + ((64 + 16 * g + 8 * sg) ^ sw)) = w;
        }
    }
    __syncthreads();

    // NOTE epilogue write above: o0[4g+t] holds d = t + 8g + 4sg (t<4), so the
    // b64 at byte (16g + 8sg) covers d = 8g+4sg .. +3 — consistent.

    // coalesced store: attn_out[b*1024+n][h*64+d] -- 128B head-chunk per row
    {
        char* dst = (char*)attn_out + ((size_t)(bh >> 3) * 1024 + mt * 128) * 1024 +
                    (bh & 7) * 128;
#pragma unroll
        for (int p = 0; p < 4; ++p) {
            int cid = p * 256 + tid;
            int row = cid >> 3, sub = cid & 7;
            s16x8 v = *(const s16x8*)(smem + row * 128 +
                                      ((sub * 16) ^ ((row & 7) << 4)));
            *(s16x8*)(dst + (size_t)row * 1024 + sub * 16) = v;
        }
    }
}

// ---- K4: out projection + LayerNorm + residual, fused -----------------------
__global__ __launch_bounds__(512) void k_out_ln(
    const u16* __restrict__ aout, const u16* __restrict__ wt,
    const float* __restrict__ bias, const float* __restrict__ x,
    const float* __restrict__ g, const float* __restrict__ bb,
    float* __restrict__ out) {
    __shared__ __align__(16) char smem[131072];  // B dbuf 2x64KB; then proj f32
    char* lB[2] = {smem, smem + 65536};
    const int tid = threadIdx.x;
    const int lane = tid & 63, l15 = lane & 15, l4 = lane >> 4;
    const int wid = tid >> 6, wm = wid >> 2, wn = wid & 3;
    const int m0 = blockIdx.x * 32;

    // A in registers: rows m0 + wm*16 + l15, k-chunk kk*32 + l4*8
    s16x8 af[16];
    {
        const char* arow = (const char*)aout + (size_t)(m0 + wm * 16 + l15) * 1024;
#pragma unroll
        for (int kk = 0; kk < 16; ++kk)
            af[kk] = *(const s16x8*)(arow + kk * 64 + l4 * 16);
    }

    auto stageB = [&](int buf, int kt) {
#pragma unroll
        for (int p = 0; p < 8; ++p) {
            int cid = p * 512 + tid;          // 0..4095 chunk id
            int n = cid >> 3, cc = cid & 7;
            int sc = (cc * 16) ^ ((n & 7) << 4);
            gl_lds16((const char*)wt + (size_t)n * 1024 + kt * 128 + sc,
                     lB[buf] + cid * 16);
        }
    };

    const f32x4 z4 = {0.f, 0.f, 0.f, 0.f};
    f32x4 acc[8];
#pragma unroll
    for (int j = 0; j < 8; ++j) acc[j] = z4;

    stageB(0, 0);
    __syncthreads();
    for (int kt = 0; kt < 8; ++kt) {
        int buf = kt & 1;
        if (kt < 7) stageB(buf ^ 1, kt + 1);
        s16x8 bf2[8][2];
#pragma unroll
        for (int j = 0; j < 8; ++j)
#pragma unroll
            for (int q = 0; q < 2; ++q) {
                int n = wn * 128 + j * 16 + l15;
                int cb = (q * 64 + l4 * 16) ^ ((n & 7) << 4);
                bf2[j][q] = *(const s16x8*)(lB[buf] + n * 128 + cb);
            }
        __builtin_amdgcn_s_setprio(1);
#pragma unroll
        for (int j = 0; j < 8; ++j)
#pragma unroll
            for (int q = 0; q < 2; ++q)
                acc[j] = MFMA16(af[kt * 2 + q], bf2[j][q], acc[j]);
        __builtin_amdgcn_s_setprio(0);
        __syncthreads();
    }

    // proj + bias -> LDS f32 [32][512], 16B-swizzled
#pragma unroll
    for (int j = 0; j < 8; ++j) {
        int col = wn * 128 + j * 16 + l15;
        float bo = bias[col];
#pragma unroll
        for (int r = 0; r < 4; ++r) {
            int row = wm * 16 + l4 * 4 + r;
            *(float*)(smem + row * 2048 + ((col * 4) ^ ((row & 7) << 4))) =
                acc[j][r] + bo;
        }
    }
    __syncthreads();

    // LN + residual: wave wid handles rows wid*4 .. +4; lane owns cols lane*8..+8
    f32x4 g0 = *(const f32x4*)(g + lane * 8);
    f32x4 g1 = *(const f32x4*)(g + lane * 8 + 4);
    f32x4 b0 = *(const f32x4*)(bb + lane * 8);
    f32x4 b1 = *(const f32x4*)(bb + lane * 8 + 4);
#pragma unroll
    for (int rr = 0; rr < 4; ++rr) {
        int row = wid * 4 + rr;
        int sw = (row & 7) << 4;
        f32x4 v0 = *(const f32x4*)(smem + row * 2048 + ((lane * 32) ^ sw));
        f32x4 v1 = *(const f32x4*)(smem + row * 2048 + ((lane * 32 + 16) ^ sw));
        float s = v0.x + v0.y + v0.z + v0.w + v1.x + v1.y + v1.z + v1.w;
        float sq = v0.x * v0.x + v0.y * v0.y + v0.z * v0.z + v0.w * v0.w +
                   v1.x * v1.x + v1.y * v1.y + v1.z * v1.z + v1.w * v1.w;
#pragma unroll
        for (int m = 1; m < 64; m <<= 1) {
            s += __shfl_xor(s, m);
            sq += __shfl_xor(sq, m);
        }
        float mu = s * (1.0f / 512.0f);
        float var = sq * (1.0f / 512.0f) - mu * mu;
        float rstd = rsqrtf(var + 1e-5f);

        const float* xr = x + (size_t)(m0 + row) * 512 + lane * 8;
        f32x4 x0 = *(const f32x4*)(xr);
        f32x4 x1 = *(const f32x4*)(xr + 4);
        f32x4 r0, r1;
#pragma unroll
        for (int u = 0; u < 4; ++u) {
            r0[u] = (v0[u] - mu) * rstd * g0[u] + b0[u] + x0[u];
            r1[u] = (v1[u] - mu) * rstd * g1[u] + b1[u] + x1[u];
        }
        float* orow = out + (size_t)(m0 + row) * 512 + lane * 8;
        *(f32x4*)(orow) = r0;
        *(f32x4*)(orow + 4) = r1;
    }
}

// ---- launch -----------------------------------------------------------------
extern "C" void kernel_launch(void* const* d_in, const int* in_sizes, int n_in,
                              void* d_out, int out_size, void* d_ws, size_t ws_size,
                              hipStream_t stream) {
    const float* x = (const float*)d_in[0];
    const float* w_qkv = (const float*)d_in[1];
    const float* w_out = (const float*)d_in[2];
    const float* b_out = (const float*)d_in[3];
    const float* ln_g = (const float*)d_in[4];
    const float* ln_b = (const float*)d_in[5];
    float* out = (float*)d_out;
    char* ws = (char*)d_ws;

    u16* xbf = (u16*)(ws + 0);             // 8 MiB   [8192][512] bf16
    u16* wqkvt = (u16*)(ws + 8388608);     // 1.5 MiB [1536][512] bf16
    u16* woutt = (u16*)(ws + 9961472);     // 0.5 MiB [512][512]  bf16
    u16* qh = (u16*)(ws + 10485760);       // 8 MiB   [64][1024][64]
    u16* kRT = (u16*)(ws + 18874368);      // 8 MiB   [64][16][8][64][8]
    u16* vT = (u16*)(ws + 27262976);       // 8 MiB   [64][64][1024]
    u16* aout = (u16*)(ws + 35651584);     // 8 MiB   [8192][512]

    k_prep<<<5120, 256, 0, stream>>>(x, w_qkv, w_out, xbf, wqkvt, woutt);
    k_qkv_gemm<<<768, 256, 0, stream>>>(xbf, wqkvt, qh, kRT, vT);
    k_attn<<<dim3(64, 8), 256, 0, stream>>>(qh, kRT, vT, aout);
    k_out_ln<<<256, 512, 0, stream>>>(aout, woutt, b_out, x, ln_g, ln_b, out);
}